// Round 7
// baseline (365.332 us; speedup 1.0000x reference)
//
#include <hip/hip_runtime.h>
#include <hip/hip_bf16.h>

typedef __bf16 bf16x8 __attribute__((ext_vector_type(8)));
typedef float f32x4 __attribute__((ext_vector_type(4)));
typedef unsigned short u16x8 __attribute__((ext_vector_type(8)));

static __device__ __forceinline__ unsigned short f2bf(float f){
  unsigned int u = __float_as_uint(f);
  u += 0x7fffu + ((u >> 16) & 1u);   // round-to-nearest-even
  return (unsigned short)(u >> 16);
}

static __device__ __forceinline__ u16x8 cvt8(const f32x4& a, const f32x4& b){
  u16x8 r;
  r[0]=f2bf(a[0]); r[1]=f2bf(a[1]); r[2]=f2bf(a[2]); r[3]=f2bf(a[3]);
  r[4]=f2bf(b[0]); r[5]=f2bf(b[1]); r[6]=f2bf(b[2]); r[7]=f2bf(b[3]);
  return r;
}

static __device__ __forceinline__ void gload16(const void* g, void* l){
  __builtin_amdgcn_global_load_lds(
      (const __attribute__((address_space(1))) unsigned int*)g,
      (__attribute__((address_space(3))) unsigned int*)l, 16, 0, 0);
}

// ---------------- mixed-staging GEMM: C[m,n] = epi( sum_k A[m,k]*B[n,k] )
// A:[M][KA] bf16 (KA = padded/loop K, mult of 32), B:[N][KB] fp32 (KB = real K, guard).
// BM=BN=128, BK=32, 4 waves (2x2 of 64x64). Double-buffered LDS (32KB), distance-2:
//   A via global_load_lds (linear [128][32] bf16, wave-uniform dest);
//   B via T14 reg-staging: fp32 global->regs issued 2 iters early, fp32->bf16 cvt at
//   LDS-write (contiguous 32B/lane, conflict-free), never at frag-read.
// Counted s_waitcnt vmcnt(6) steady state (6 VMEM ops/iter/thread: 2 gload_lds + 4 dwordx4).
// EPI 0: Cf = acc + bias(optional)  EPI 1: atomicAdd(Cf, acc)  EPI 2: Cbf = bf16(tanh(acc+bias))
template<int EPI>
__global__ __launch_bounds__(256) void gemm_mx(
    const unsigned short* __restrict__ A, const float* __restrict__ Bw,
    const float* __restrict__ bias,
    float* __restrict__ Cf, unsigned short* __restrict__ Cbf,
    int M, int N, int KA, int KB, int kchunk)
{
  constexpr int BK = 32, BUFE = 8192;                 // elems per buffer (A 4096 + B 4096)
  __shared__ unsigned short lds[2 * BUFE];            // 32 KB

  const int tid  = threadIdx.x, lane = tid & 63, wave = tid >> 6;
  const int bm0  = blockIdx.y * 128, bn0 = blockIdx.x * 128;
  const int k0   = blockIdx.z * kchunk;
  const int kend = min(KA, k0 + kchunk);
  const int nk   = (kend - k0) / BK;                  // kchunk mult of 32
  const int fr = lane & 15, fq = lane >> 4;
  const int wm = (wave >> 1) * 64, wn = (wave & 1) * 64;

  // A-DMA geometry: call c -> LDS bytes [wave*2048 + c*1024, +1024), HW adds lane*16.
  const int arow0 = bm0 + wave * 32 + (lane >> 2);    // +c*16 ; clamped to M-1
  const int acol  = (lane & 3) * 8;
  // B reg geometry: 2 threads/row, 16 f32 each.
  const int brow = min(bn0 + (tid >> 1), N - 1);
  const int bcol = (tid & 1) * 16;
  const float* Brow = Bw + (size_t)brow * KB;

  auto stageA = [&](int buf, int t){
    unsigned short* dst = lds + buf * BUFE;
    const int kk = k0 + t * BK;
    #pragma unroll
    for (int c = 0; c < 2; c++) {
      const int r = min(arow0 + c * 16, M - 1);
      gload16(A + (size_t)r * KA + kk + acol,
              (char*)dst + wave * 2048 + c * 1024);   // wave-uniform dest
    }
  };
  auto loadB = [&](int t, f32x4 (&rb)[4]){
    const int kk = k0 + t * BK + bcol;
    #pragma unroll
    for (int q = 0; q < 4; q++) {
      const int c = kk + q * 4;
      const f32x4 v = *(const f32x4*)(Brow + min(c, KB - 4)); // clamped: always in-bounds
      const f32x4 z4 = {0.f,0.f,0.f,0.f};
      rb[q] = (c < KB) ? v : z4;                      // zero pad beyond real K
    }
  };
  auto writeB = [&](int buf, const f32x4 (&rb)[4]){
    unsigned short* d = lds + buf * BUFE + 4096 + (tid >> 1) * 32 + (tid & 1) * 16;
    *(u16x8*)(d)     = cvt8(rb[0], rb[1]);
    *(u16x8*)(d + 8) = cvt8(rb[2], rb[3]);
  };

  f32x4 rb0[4], rb1[4];
  stageA(0, 0); loadB(0, rb0);
  if (nk > 1) { stageA(1, 1); loadB(1, rb1); }

  f32x4 acc[4][4] = {};
  int t = 0;

  auto iter = [&](f32x4 (&rb)[4]){
    if (t < nk - 1) asm volatile("s_waitcnt vmcnt(6)" ::: "memory");
    else            asm volatile("s_waitcnt vmcnt(0)" ::: "memory");
    writeB(t & 1, rb);                                 // B(t) regs -> LDS (cvt here)
    asm volatile("s_waitcnt lgkmcnt(0)" ::: "memory"); // my ds_writes committed
    __builtin_amdgcn_sched_barrier(0);
    __builtin_amdgcn_s_barrier();                      // tile t (A-DMA + B-writes) visible

    const unsigned short* lA = lds + (t & 1) * BUFE;
    const unsigned short* lB = lA + 4096;
    u16x8 af[4], bg[4];
    #pragma unroll
    for (int i = 0; i < 4; i++) af[i] = *(const u16x8*)&lA[(wm + i*16 + fr) * BK + fq * 8];
    #pragma unroll
    for (int j = 0; j < 4; j++) bg[j] = *(const u16x8*)&lB[(wn + j*16 + fr) * BK + fq * 8];
    asm volatile("s_waitcnt lgkmcnt(0)" ::: "memory"); // frag reads in regs
    __builtin_amdgcn_sched_barrier(0);
    __builtin_amdgcn_s_barrier();                      // all waves done with buf (t&1)

    if (t + 2 < nk) { stageA(t & 1, t + 2); loadB(t + 2, rb); } // refill freed buffer

    #pragma unroll
    for (int i = 0; i < 4; i++)
      #pragma unroll
      for (int j = 0; j < 4; j++)
        acc[i][j] = __builtin_amdgcn_mfma_f32_16x16x32_bf16(
            __builtin_bit_cast(bf16x8, af[i]),
            __builtin_bit_cast(bf16x8, bg[j]),
            acc[i][j], 0, 0, 0);
    ++t;
  };

  while (t + 1 < nk) { iter(rb0); iter(rb1); }         // even/odd named reg sets
  if (t < nk) iter(rb0);                               // odd nk tail (t even)

  #pragma unroll
  for (int i = 0; i < 4; i++)
    #pragma unroll
    for (int j = 0; j < 4; j++)
      #pragma unroll
      for (int r = 0; r < 4; r++) {
        int row = bm0 + wm + i*16 + fq*4 + r;
        int col = bn0 + wn + j*16 + fr;
        if (row < M && col < N) {
          float v = acc[i][j][r];
          if constexpr (EPI == 0) {
            Cf[(size_t)row * N + col] = v + (bias ? bias[col] : 0.0f);
          } else if constexpr (EPI == 1) {
            atomicAdd(&Cf[(size_t)row * N + col], v);
          } else {
            Cbf[(size_t)row * N + col] = f2bf(tanhf(v + bias[col]));
          }
        }
      }
}

// fp32 [rows][scols] -> bf16 [rows][dcols], zero-padded (dcols mult of 8)
__global__ __launch_bounds__(256) void cvtpad_kernel(
    const float* __restrict__ src, unsigned short* __restrict__ dst,
    int rows, int scols, int dcols)
{
  int i8 = blockIdx.x * 256 + threadIdx.x;
  int c8 = dcols / 8;
  if (i8 >= rows * c8) return;
  int r = i8 / c8, c0 = (i8 % c8) * 8;
  const float* s = src + (size_t)r * scols;
  u16x8 o;
  #pragma unroll
  for (int e = 0; e < 8; e++) { int c = c0 + e; o[e] = (c < scols) ? f2bf(s[c]) : (unsigned short)0; }
  *(u16x8*)(dst + (size_t)r * dcols + c0) = o;
}

// ---------------- elementwise / reduction kernels ----------------
__global__ __launch_bounds__(256) void ynorm_kernel(
    const float* __restrict__ x, const float* __restrict__ dm,
    unsigned short* __restrict__ y, float* __restrict__ ninv, int D0)
{
  const int b = blockIdx.x, tid = threadIdx.x;
  const float4* x4 = (const float4*)(x + (size_t)b * D0);
  const float4* d4 = (const float4*)(dm + (size_t)b * D0);
  ushort4* y4 = (ushort4*)(y + (size_t)b * D0);
  const int n4 = D0 / 4;
  float ss = 0.f;
  for (int i = tid; i < n4; i += 256) {
    float4 xv = x4[i], dv = d4[i];
    ss += xv.x*xv.x + xv.y*xv.y + xv.z*xv.z + xv.w*xv.w;
    ushort4 o;
    o.x = f2bf(xv.x*dv.x); o.y = f2bf(xv.y*dv.y);
    o.z = f2bf(xv.z*dv.z); o.w = f2bf(xv.w*dv.w);
    y4[i] = o;
  }
  #pragma unroll
  for (int off = 32; off > 0; off >>= 1) ss += __shfl_down(ss, off);
  __shared__ float wsum[4];
  if ((tid & 63) == 0) wsum[tid >> 6] = ss;
  __syncthreads();
  if (tid == 0) {
    float t = wsum[0] + wsum[1] + wsum[2] + wsum[3];
    ninv[b] = 1.0f / fmaxf(sqrtf(t), 1e-12f);
  }
}

__global__ __launch_bounds__(256) void stats_kernel(
    const float* __restrict__ proj, const int* __restrict__ ids,
    const float* __restrict__ bi, const float* __restrict__ eps,
    float* __restrict__ prior, int T)
{
  const int b = blockIdx.x, l = threadIdx.x;
  __shared__ int sid[256];
  if (l < T) sid[l] = ids[b * T + l];
  __syncthreads();
  float s1 = 0.f, s2 = 0.f;
  #pragma unroll 4
  for (int t = 0; t < T; t++) {
    float p = proj[(size_t)sid[t] * 256 + l];
    s1 += p; s2 += p * p;
  }
  float var = fmaxf((s2 - s1 * s1 / (float)T) / (float)(T - 1), 0.f);
  float dev = sqrtf(var);
  float mean = s1 / (float)T + bi[l];
  prior[b * 256 + l] = mean + sqrtf(dev) * eps[b * 256 + l];
}

__global__ __launch_bounds__(256) void epi1_kernel(
    const float* __restrict__ C1, const float* __restrict__ ninv,
    const float* __restrict__ be1, unsigned short* __restrict__ h)
{
  int i = blockIdx.x * 256 + threadIdx.x;
  int b = i >> 10, n = i & 1023;
  h[i] = f2bf(tanhf(ninv[b] * C1[i] + be1[n]));
}

__global__ __launch_bounds__(256) void z_kernel(
    const float* __restrict__ gp, const float* __restrict__ prior,
    const float* __restrict__ be2,
    float* __restrict__ out_mu, float* __restrict__ out_lv,
    unsigned short* __restrict__ z)
{
  int i = blockIdx.x * 256 + threadIdx.x;
  int b = i >> 8, l = i & 255;
  float mu = gp[b * 512 + l]       + be2[l];
  float lv = gp[b * 512 + 256 + l] + be2[256 + l];
  out_mu[i] = mu;
  out_lv[i] = lv;
  z[i] = f2bf(prior[i] * expf(0.5f * lv) + mu);
}

extern "C" void kernel_launch(void* const* d_in, const int* in_sizes, int n_in,
                              void* d_out, int out_size, void* d_ws, size_t ws_size,
                              hipStream_t stream)
{
  const float* x     = (const float*)d_in[0];
  const int*   ids   = (const int*)  d_in[1];
  const float* embed = (const float*)d_in[2];
  const float* Wi    = (const float*)d_in[3];
  const float* bi    = (const float*)d_in[4];
  const float* We1   = (const float*)d_in[5];
  const float* be1   = (const float*)d_in[6];
  const float* We2   = (const float*)d_in[7];
  const float* be2   = (const float*)d_in[8];
  const float* Wd1   = (const float*)d_in[9];
  const float* bd1   = (const float*)d_in[10];
  const float* Wd2   = (const float*)d_in[11];
  const float* bd2   = (const float*)d_in[12];
  const float* dm    = (const float*)d_in[13];
  const float* eps   = (const float*)d_in[14];

  constexpr int B = 512, T = 200, V = 3356, E = 1128, Ep = 1152, D0 = 20000, H = 1024, L = 256;

  char* w = (char*)d_ws;
  auto carve = [&](size_t bytes) { char* p = w; w += (bytes + 255) & ~(size_t)255; return p; };
  unsigned short* embedb= (unsigned short*)carve((size_t)V * Ep * 2);   // 7.7 MB
  float*          proj  = (float*)         carve((size_t)V * L * 4);    // 3.4 MB
  unsigned short* y     = (unsigned short*)carve((size_t)B * D0 * 2);   // 20.5 MB
  float*          C1    = (float*)         carve((size_t)B * H * 4);
  unsigned short* h     = (unsigned short*)carve((size_t)B * H * 2);
  float*          gp    = (float*)         carve((size_t)B * 2 * L * 4);
  float*          prior = (float*)         carve((size_t)B * L * 4);
  unsigned short* z     = (unsigned short*)carve((size_t)B * L * 2);
  unsigned short* hd    = (unsigned short*)carve((size_t)B * H * 2);
  float*          ninv  = (float*)         carve((size_t)B * 4);

  float* out_recon = (float*)d_out;
  float* out_mu    = out_recon + (size_t)B * D0;
  float* out_lv    = out_mu + (size_t)B * L;

  // embed -> bf16 padded (A operand of proj); all B operands stay fp32 (converted in-GEMM)
  cvtpad_kernel<<<(V * (Ep/8) + 255) / 256, 256, 0, stream>>>(embed, embedb, V, E, Ep);

  // y = bf16(x*dm), ninv = 1/||x||
  ynorm_kernel<<<B, 256, 0, stream>>>(x, dm, y, ninv, D0);

  // proj = embedb @ Wi^T  (M=3356, N=256, KA=1152, KB=1128), split-K=4
  hipMemsetAsync(proj, 0, (size_t)V * L * 4, stream);
  gemm_mx<1><<<dim3(2, 27, 4), 256, 0, stream>>>(
      embedb, Wi, nullptr, proj, nullptr, V, L, Ep, E, 288);
  // prior from gathered stats (adds bi)
  stats_kernel<<<B, 256, 0, stream>>>(proj, ids, bi, eps, prior, T);

  // GEMM1: C1 = y @ We1^T  (M=512, N=1024, K=20000), split-K=25
  hipMemsetAsync(C1, 0, (size_t)B * H * 4, stream);
  gemm_mx<1><<<dim3(8, 4, 25), 256, 0, stream>>>(
      y, We1, nullptr, C1, nullptr, B, H, D0, D0, 800);
  // h = tanh(ninv*C1 + be1)
  epi1_kernel<<<(B * H) / 256, 256, 0, stream>>>(C1, ninv, be1, h);

  // gparams = h @ We2^T (+be2 in z_kernel)  (M=512, N=512, K=1024), split-K=4
  hipMemsetAsync(gp, 0, (size_t)B * 2 * L * 4, stream);
  gemm_mx<1><<<dim3(4, 4, 4), 256, 0, stream>>>(
      h, We2, nullptr, gp, nullptr, B, 2 * L, H, H, 256);
  // mu/logvar out, z
  z_kernel<<<(B * L) / 256, 256, 0, stream>>>(gp, prior, be2, out_mu, out_lv, z);

  // hd = tanh(z @ Wd1^T + bd1)  (M=512, N=1024, K=256)
  gemm_mx<2><<<dim3(8, 4, 1), 256, 0, stream>>>(
      z, Wd1, bd1, nullptr, hd, B, H, L, L, 256);
  // recon = hd @ Wd2^T + bd2   (M=512, N=20000, K=1024)
  gemm_mx<0><<<dim3(157, 4, 1), 256, 0, stream>>>(
      hd, Wd2, bd2, out_recon, nullptr, B, D0, H, H, 1024);
}